// Round 1
// baseline (272.930 us; speedup 1.0000x reference)
//
#include <hip/hip_runtime.h>
#include <stdint.h>

typedef unsigned short ushort_t;
typedef __attribute__((ext_vector_type(4))) float f32x4;
typedef __attribute__((ext_vector_type(8))) short short8;

#define LDS_AS __attribute__((address_space(3)))
#define GLB_AS __attribute__((address_space(1)))

__device__ __forceinline__ ushort_t f2bf(float f) {
    uint32_t u = __float_as_uint(f);
    u += 0x7FFFu + ((u >> 16) & 1u);   // RNE
    return (ushort_t)(u >> 16);
}

__device__ __forceinline__ float blocksum256(float v) {
    __shared__ float sm[4];
    #pragma unroll
    for (int off = 32; off > 0; off >>= 1) v += __shfl_down(v, off);
    if ((threadIdx.x & 63) == 0) sm[threadIdx.x >> 6] = v;
    __syncthreads();
    float r = sm[0] + sm[1] + sm[2] + sm[3];
    __syncthreads();
    return r;
}

// ---------- l2-normalize rows of [nrows, 768] f32 -> f32 ----------
__global__ __launch_bounds__(256) void k_norm_f32(const float* __restrict__ src, float* __restrict__ dst) {
    int r = blockIdx.x, t = threadIdx.x;
    const float* x = src + (size_t)r * 768;
    float a0 = x[t], a1 = x[t + 256], a2 = x[t + 512];
    float ss = blocksum256(a0 * a0 + a1 * a1 + a2 * a2);
    float sc = 1.0f / fmaxf(sqrtf(ss), 1e-12f);
    float* d = dst + (size_t)r * 768;
    d[t] = a0 * sc; d[t + 256] = a1 * sc; d[t + 512] = a2 * sc;
}

// ---------- l2-normalize rows -> bf16 ----------
__global__ __launch_bounds__(256) void k_norm_bf16(const float* __restrict__ src, ushort_t* __restrict__ dst) {
    int r = blockIdx.x, t = threadIdx.x;
    const float* x = src + (size_t)r * 768;
    float a0 = x[t], a1 = x[t + 256], a2 = x[t + 512];
    float ss = blocksum256(a0 * a0 + a1 * a1 + a2 * a2);
    float sc = 1.0f / fmaxf(sqrtf(ss), 1e-12f);
    ushort_t* d = dst + (size_t)r * 768;
    d[t] = f2bf(a0 * sc); d[t + 256] = f2bf(a1 * sc); d[t + 512] = f2bf(a2 * sc);
}

// ---------- aggregate text: mean over 32 candidates, then l2norm ----------
__global__ __launch_bounds__(256) void k_agg_norm(const float* __restrict__ cand, float* __restrict__ an) {
    int b = blockIdx.x, t = threadIdx.x;
    const float* c = cand + (size_t)b * 32 * 768;
    float m0 = 0.f, m1 = 0.f, m2 = 0.f;
    for (int k = 0; k < 32; ++k) {
        const float* ck = c + k * 768;
        m0 += ck[t]; m1 += ck[t + 256]; m2 += ck[t + 512];
    }
    m0 *= (1.0f / 32.0f); m1 *= (1.0f / 32.0f); m2 *= (1.0f / 32.0f);
    float ss = blocksum256(m0 * m0 + m1 * m1 + m2 * m2);
    float sc = 1.0f / fmaxf(sqrtf(ss), 1e-12f);
    float* d = an + (size_t)b * 768;
    d[t] = m0 * sc; d[t + 256] = m1 * sc; d[t + 512] = m2 * sc;
}

// ---------- small logits matrices + row LSE ----------
// blocks 0..127: L1 = vn@tn^T *10 ; 128..255: L3 = vn@an^T ; 256..383: L4 = tn@an^T ;
// 384..639: NT = z@z^T *10, diag=-1e9 (z = [vn;tn])
__global__ __launch_bounds__(256) void k_logits(
    const float* __restrict__ vn, const float* __restrict__ tn, const float* __restrict__ an,
    float* __restrict__ L1, float* __restrict__ L3, float* __restrict__ L4, float* __restrict__ NT,
    float* __restrict__ lse_r)
{
    __shared__ __align__(16) float xrow[768];
    __shared__ float red[256];
    int blk = blockIdx.x, t = threadIdx.x;
    int task, i, nc; const float* xp; float* M; int lseoff;
    if (blk < 128)      { task = 0; i = blk;       nc = 128; xp = vn + (size_t)i * 768; M = L1; lseoff = 0; }
    else if (blk < 256) { task = 1; i = blk - 128; nc = 128; xp = vn + (size_t)i * 768; M = L3; lseoff = 128; }
    else if (blk < 384) { task = 2; i = blk - 256; nc = 128; xp = tn + (size_t)i * 768; M = L4; lseoff = 256; }
    else                { task = 3; i = blk - 384; nc = 256;
                          xp = (i < 128) ? vn + (size_t)i * 768 : tn + (size_t)(i - 128) * 768;
                          M = NT; lseoff = 384; }
    for (int d = t; d < 768; d += 256) xrow[d] = xp[d];
    __syncthreads();
    int j = t;
    float v = -1e30f;
    if (j < nc) {
        const float* yp;
        if (task == 0)      yp = tn + (size_t)j * 768;
        else if (task == 3) yp = (j < 128) ? vn + (size_t)j * 768 : tn + (size_t)(j - 128) * 768;
        else                yp = an + (size_t)j * 768;
        const float4* y4 = (const float4*)yp;
        const float4* x4 = (const float4*)xrow;
        float s = 0.0f;
        #pragma unroll 4
        for (int d = 0; d < 192; ++d) {
            float4 a = x4[d], b = y4[d];
            s += a.x * b.x + a.y * b.y + a.z * b.z + a.w * b.w;
        }
        v = s * 10.0f;                       // /temp
        if (task == 3 && j == i) v = -1e9f;  // self mask
        M[(size_t)i * nc + j] = v;
    }
    // row logsumexp over j < nc
    red[t] = (j < nc) ? v : -1e30f;
    __syncthreads();
    for (int off = 128; off > 0; off >>= 1) { if (t < off) red[t] = fmaxf(red[t], red[t + off]); __syncthreads(); }
    float mx = red[0];
    __syncthreads();
    red[t] = (j < nc) ? expf(v - mx) : 0.0f;
    __syncthreads();
    for (int off = 128; off > 0; off >>= 1) { if (t < off) red[t] += red[t + off]; __syncthreads(); }
    if (t == 0) lse_r[lseoff + i] = mx + logf(red[0]);
}

// ---------- column LSE for L1/L3/L4 ----------
__global__ __launch_bounds__(128) void k_collse(
    const float* __restrict__ L1, const float* __restrict__ L3, const float* __restrict__ L4,
    float* __restrict__ lse_c)
{
    __shared__ float sm[128];
    int blk = blockIdx.x; int mat = blk >> 7; int j = blk & 127; int i = threadIdx.x;
    const float* M = (mat == 0) ? L1 : (mat == 1 ? L3 : L4);
    float v = M[(size_t)i * 128 + j];
    sm[i] = v; __syncthreads();
    for (int off = 64; off > 0; off >>= 1) { if (i < off) sm[i] = fmaxf(sm[i], sm[i + off]); __syncthreads(); }
    float mx = sm[0]; __syncthreads();
    sm[i] = expf(v - mx); __syncthreads();
    for (int off = 64; off > 0; off >>= 1) { if (i < off) sm[i] += sm[i + off]; __syncthreads(); }
    if (i == 0) lse_c[mat * 128 + j] = mx + logf(sm[0]);
}

// ---------- big GEMM: S[8192, ldS] (bf16) = A[8192,768] @ B[ldS rows,768]^T ----------
__global__ __launch_bounds__(256) void k_gemm(
    const ushort_t* __restrict__ A, const ushort_t* __restrict__ B,
    ushort_t* __restrict__ S, int ldS, int K)
{
    __shared__ ushort_t As[128 * 64];
    __shared__ ushort_t Bs[128 * 64];
    const int t = threadIdx.x;
    const int lane = t & 63, w = t >> 6;
    const int wr = w >> 1, wc = w & 1;
    const int m0 = blockIdx.x * 128, n0 = blockIdx.y * 128;
    const int lr = lane & 15, lk = lane >> 4;

    f32x4 acc[4][4] = {};

    for (int k0 = 0; k0 < K; k0 += 64) {
        #pragma unroll
        for (int ii = 0; ii < 4; ++ii) {
            int idx = ii * 256 + t;
            int row = idx >> 3, kc = (idx & 7) * 8;
            __builtin_amdgcn_global_load_lds(
                (const GLB_AS void*)(A + (size_t)(m0 + row) * K + (k0 + kc)),
                (LDS_AS void*)(As + idx * 8), 16, 0, 0);
        }
        #pragma unroll
        for (int ii = 0; ii < 4; ++ii) {
            int idx = ii * 256 + t;
            int row = idx >> 3, kc = (idx & 7) * 8;
            __builtin_amdgcn_global_load_lds(
                (const GLB_AS void*)(B + (size_t)(n0 + row) * K + (k0 + kc)),
                (LDS_AS void*)(Bs + idx * 8), 16, 0, 0);
        }
        __syncthreads();
        #pragma unroll
        for (int kk = 0; kk < 2; ++kk) {
            short8 av[4], bv[4];
            #pragma unroll
            for (int f = 0; f < 4; ++f)
                av[f] = *(const short8*)(As + (wr * 64 + f * 16 + lr) * 64 + kk * 32 + lk * 8);
            #pragma unroll
            for (int f = 0; f < 4; ++f)
                bv[f] = *(const short8*)(Bs + (wc * 64 + f * 16 + lr) * 64 + kk * 32 + lk * 8);
            #pragma unroll
            for (int fr = 0; fr < 4; ++fr)
                #pragma unroll
                for (int fc = 0; fc < 4; ++fc)
                    acc[fr][fc] = __builtin_amdgcn_mfma_f32_16x16x32_bf16(av[fr], bv[fc], acc[fr][fc], 0, 0, 0);
        }
        __syncthreads();
    }
    #pragma unroll
    for (int fr = 0; fr < 4; ++fr) {
        #pragma unroll
        for (int fc = 0; fc < 4; ++fc) {
            int col = n0 + wc * 64 + fc * 16 + lr;
            #pragma unroll
            for (int q = 0; q < 4; ++q) {
                int row = m0 + wr * 64 + fr * 16 + lk * 4 + q;
                S[(size_t)row * ldS + col] = f2bf(acc[fr][fc][q]);
            }
        }
    }
}

// ---------- soft-DTW DP: one wave per (b,g) problem, lane = row f, anti-diagonal skew ----------
__global__ __launch_bounds__(256) void k_dtw(
    const ushort_t* __restrict__ S, float* __restrict__ Dm,
    int ldS, int g0, int GC)
{
    __shared__ float cst[4][2048];
    const float K10 = 14.4269504088896340f;   // 10 * log2(e); cost pre-scaled so softmin needs no muls
    const int t = threadIdx.x, lane = t & 63, w = t >> 6;
    int p = blockIdx.x * 4 + w;
    int b = p / GC, gg = p - b * GC;
    const ushort_t* srow = S + (size_t)(b * 64 + lane) * ldS + gg * 32;
    float* my = cst[w];
    const uint4* s4 = (const uint4*)srow;
    #pragma unroll
    for (int q = 0; q < 4; ++q) {
        uint4 vv = s4[q];
        uint32_t uu[4] = {vv.x, vv.y, vv.z, vv.w};
        #pragma unroll
        for (int h = 0; h < 4; ++h) {
            float lo = __uint_as_float(uu[h] << 16);
            float hi = __uint_as_float(uu[h] & 0xFFFF0000u);
            my[lane * 32 + q * 8 + h * 2 + 0] = (1.0f - lo) * K10;
            my[lane * 32 + q * 8 + h * 2 + 1] = (1.0f - hi) * K10;
        }
    }
    __syncthreads();
    const float BIG = 1e30f;
    float rp = BIG, rp2 = BIG;
    const float* base = my + lane * 31;       // base[s] == my[lane*32 + (s - lane)]
    for (int s = 0; s < 95; ++s) {
        float up = __shfl_up(rp, 1);
        float dg = __shfl_up(rp2, 1);
        if (lane == 0) { up = BIG; dg = (s == 0) ? 0.0f : BIG; }
        float c = base[s];
        float mn = fminf(fminf(rp, up), dg);
        float e = exp2f(mn - rp) + exp2f(mn - up) + exp2f(mn - dg);
        float r = c + mn - log2f(e);
        if ((unsigned)(s - lane) < 32u) { rp2 = rp; rp = r; }
    }
    if (lane == 63) Dm[b * 128 + g0 + gg] = rp * (1.0f / K10);
}

// ---------- finalize: all CE losses + DTW CE -> scalar ----------
__global__ __launch_bounds__(128) void k_finalize(
    const float* __restrict__ L1, const float* __restrict__ L3, const float* __restrict__ L4,
    const float* __restrict__ NT, const float* __restrict__ lse_r, const float* __restrict__ lse_c,
    const float* __restrict__ Dm, float* __restrict__ out)
{
    int i = threadIdx.x;
    float d1 = L1[(size_t)i * 128 + i];
    float l1 = 0.5f * ((lse_r[i] - d1) + (lse_c[i] - d1));
    float d3 = L3[(size_t)i * 128 + i];
    float l3 = 0.5f * ((lse_r[128 + i] - d3) + (lse_c[128 + i] - d3));
    float d4 = L4[(size_t)i * 128 + i];
    float l4 = 0.5f * ((lse_r[256 + i] - d4) + (lse_c[256 + i] - d4));
    float nt = 0.5f * (lse_r[384 + i] - NT[(size_t)i * 256 + i + 128])
             + 0.5f * (lse_r[384 + 128 + i] - NT[(size_t)(i + 128) * 256 + i]);
    float mxr = -1e30f, mxc = -1e30f;
    for (int j = 0; j < 128; ++j) {
        mxr = fmaxf(mxr, -10.0f * Dm[i * 128 + j]);
        mxc = fmaxf(mxc, -10.0f * Dm[j * 128 + i]);
    }
    float sr = 0.f, sc2 = 0.f;
    for (int j = 0; j < 128; ++j) {
        sr  += expf(-10.0f * Dm[i * 128 + j] - mxr);
        sc2 += expf(-10.0f * Dm[j * 128 + i] - mxc);
    }
    float dd = -10.0f * Dm[i * 128 + i];
    float ld = 0.5f * ((mxr + logf(sr) - dd) + (mxc + logf(sc2) - dd));
    float tot = l1 + l3 + l4 + nt + 0.1f * ld;
    #pragma unroll
    for (int o = 32; o > 0; o >>= 1) tot += __shfl_down(tot, o);
    __shared__ float sm[2];
    if ((i & 63) == 0) sm[i >> 6] = tot;
    __syncthreads();
    if (i == 0) out[0] = (sm[0] + sm[1]) / (128.0f * 5.0f);
}

extern "C" void kernel_launch(void* const* d_in, const int* in_sizes, int n_in,
                              void* d_out, int out_size, void* d_ws, size_t ws_size,
                              hipStream_t stream)
{
    (void)in_sizes; (void)n_in; (void)out_size;
    const float* video = (const float*)d_in[0];   // [128,768]
    const float* sent  = (const float*)d_in[1];   // [128,768]
    const float* cand  = (const float*)d_in[2];   // [128,32,768]
    const float* frame = (const float*)d_in[3];   // [128,64,768]
    // d_in[4] = pos_step: unused by the reference.

    char* ws = (char*)d_ws;
    size_t off = 0;
    auto alloc = [&](size_t b) { void* p = ws + off; off = (off + b + 255) & ~(size_t)255; return p; };
    float*    vn  = (float*)alloc((size_t)128 * 768 * 4);
    float*    tn  = (float*)alloc((size_t)128 * 768 * 4);
    float*    an  = (float*)alloc((size_t)128 * 768 * 4);
    ushort_t* Abf = (ushort_t*)alloc((size_t)8192 * 768 * 2);
    ushort_t* Bbf = (ushort_t*)alloc((size_t)4096 * 768 * 2);
    float*    L1  = (float*)alloc((size_t)128 * 128 * 4);
    float*    L3  = (float*)alloc((size_t)128 * 128 * 4);
    float*    L4  = (float*)alloc((size_t)128 * 128 * 4);
    float*    NT  = (float*)alloc((size_t)256 * 256 * 4);
    float*    lse_r = (float*)alloc((size_t)640 * 4);
    float*    lse_c = (float*)alloc((size_t)384 * 4);
    float*    Dm  = (float*)alloc((size_t)128 * 128 * 4);
    int Nch = 4096;                                  // S chunk width; shrink if ws too small
    while (Nch > 128 && off + (size_t)Nch * 8192 * 2 > ws_size) Nch >>= 1;
    ushort_t* S = (ushort_t*)alloc((size_t)Nch * 8192 * 2);

    k_norm_f32 <<<128, 256, 0, stream>>>(video, vn);
    k_norm_f32 <<<128, 256, 0, stream>>>(sent, tn);
    k_agg_norm <<<128, 256, 0, stream>>>(cand, an);
    k_norm_bf16<<<8192, 256, 0, stream>>>(frame, Abf);
    k_norm_bf16<<<4096, 256, 0, stream>>>(cand, Bbf);
    k_logits   <<<640, 256, 0, stream>>>(vn, tn, an, L1, L3, L4, NT, lse_r);
    k_collse   <<<384, 128, 0, stream>>>(L1, L3, L4, lse_c);
    for (int c0 = 0; c0 < 4096; c0 += Nch) {
        int GC = Nch / 32;
        k_gemm<<<dim3(64, Nch / 128), 256, 0, stream>>>(Abf, Bbf + (size_t)c0 * 768, S, Nch, 768);
        k_dtw <<<dim3(128 * GC / 4), 256, 0, stream>>>(S, Dm, Nch, c0 / 32, GC);
    }
    k_finalize <<<1, 128, 0, stream>>>(L1, L3, L4, NT, lse_r, lse_c, Dm, (float*)d_out);
}

// Round 2
// 209.512 us; speedup vs baseline: 1.3027x; 1.3027x over previous
//
#include <hip/hip_runtime.h>
#include <stdint.h>

typedef unsigned short ushort_t;
typedef __attribute__((ext_vector_type(4))) float f32x4;
typedef __attribute__((ext_vector_type(8))) short short8;

#define LDS_AS __attribute__((address_space(3)))
#define GLB_AS __attribute__((address_space(1)))

__device__ __forceinline__ ushort_t f2bf(float f) {
    uint32_t u = __float_as_uint(f);
    u += 0x7FFFu + ((u >> 16) & 1u);   // RNE
    return (ushort_t)(u >> 16);
}

__device__ __forceinline__ float blocksum256(float v) {
    __shared__ float sm[4];
    #pragma unroll
    for (int off = 32; off > 0; off >>= 1) v += __shfl_down(v, off);
    if ((threadIdx.x & 63) == 0) sm[threadIdx.x >> 6] = v;
    __syncthreads();
    float r = sm[0] + sm[1] + sm[2] + sm[3];
    __syncthreads();
    return r;
}

// ---------- l2-normalize rows of [nrows, 768] f32 -> f32 ----------
__global__ __launch_bounds__(256) void k_norm_f32(const float* __restrict__ src, float* __restrict__ dst) {
    int r = blockIdx.x, t = threadIdx.x;
    const float* x = src + (size_t)r * 768;
    float a0 = x[t], a1 = x[t + 256], a2 = x[t + 512];
    float ss = blocksum256(a0 * a0 + a1 * a1 + a2 * a2);
    float sc = 1.0f / fmaxf(sqrtf(ss), 1e-12f);
    float* d = dst + (size_t)r * 768;
    d[t] = a0 * sc; d[t + 256] = a1 * sc; d[t + 512] = a2 * sc;
}

// ---------- l2-normalize rows -> bf16 ----------
__global__ __launch_bounds__(256) void k_norm_bf16(const float* __restrict__ src, ushort_t* __restrict__ dst) {
    int r = blockIdx.x, t = threadIdx.x;
    const float* x = src + (size_t)r * 768;
    float a0 = x[t], a1 = x[t + 256], a2 = x[t + 512];
    float ss = blocksum256(a0 * a0 + a1 * a1 + a2 * a2);
    float sc = 1.0f / fmaxf(sqrtf(ss), 1e-12f);
    ushort_t* d = dst + (size_t)r * 768;
    d[t] = f2bf(a0 * sc); d[t + 256] = f2bf(a1 * sc); d[t + 512] = f2bf(a2 * sc);
}

// ---------- aggregate text: mean over 32 candidates, then l2norm ----------
__global__ __launch_bounds__(256) void k_agg_norm(const float* __restrict__ cand, float* __restrict__ an) {
    int b = blockIdx.x, t = threadIdx.x;
    const float* c = cand + (size_t)b * 32 * 768;
    float m0 = 0.f, m1 = 0.f, m2 = 0.f;
    for (int k = 0; k < 32; ++k) {
        const float* ck = c + k * 768;
        m0 += ck[t]; m1 += ck[t + 256]; m2 += ck[t + 512];
    }
    m0 *= (1.0f / 32.0f); m1 *= (1.0f / 32.0f); m2 *= (1.0f / 32.0f);
    float ss = blocksum256(m0 * m0 + m1 * m1 + m2 * m2);
    float sc = 1.0f / fmaxf(sqrtf(ss), 1e-12f);
    float* d = an + (size_t)b * 768;
    d[t] = m0 * sc; d[t + 256] = m1 * sc; d[t + 512] = m2 * sc;
}

// ---------- small logits matrices + row LSE ----------
// blocks 0..127: L1 = vn@tn^T *10 ; 128..255: L3 = vn@an^T ; 256..383: L4 = tn@an^T ;
// 384..639: NT = z@z^T *10, diag=-1e9 (z = [vn;tn])
__global__ __launch_bounds__(256) void k_logits(
    const float* __restrict__ vn, const float* __restrict__ tn, const float* __restrict__ an,
    float* __restrict__ L1, float* __restrict__ L3, float* __restrict__ L4, float* __restrict__ NT,
    float* __restrict__ lse_r)
{
    __shared__ __align__(16) float xrow[768];
    __shared__ float red[256];
    int blk = blockIdx.x, t = threadIdx.x;
    int task, i, nc; const float* xp; float* M; int lseoff;
    if (blk < 128)      { task = 0; i = blk;       nc = 128; xp = vn + (size_t)i * 768; M = L1; lseoff = 0; }
    else if (blk < 256) { task = 1; i = blk - 128; nc = 128; xp = vn + (size_t)i * 768; M = L3; lseoff = 128; }
    else if (blk < 384) { task = 2; i = blk - 256; nc = 128; xp = tn + (size_t)i * 768; M = L4; lseoff = 256; }
    else                { task = 3; i = blk - 384; nc = 256;
                          xp = (i < 128) ? vn + (size_t)i * 768 : tn + (size_t)(i - 128) * 768;
                          M = NT; lseoff = 384; }
    for (int d = t; d < 768; d += 256) xrow[d] = xp[d];
    __syncthreads();
    int j = t;
    float v = -1e30f;
    if (j < nc) {
        const float* yp;
        if (task == 0)      yp = tn + (size_t)j * 768;
        else if (task == 3) yp = (j < 128) ? vn + (size_t)j * 768 : tn + (size_t)(j - 128) * 768;
        else                yp = an + (size_t)j * 768;
        const float4* y4 = (const float4*)yp;
        const float4* x4 = (const float4*)xrow;
        float s = 0.0f;
        #pragma unroll 4
        for (int d = 0; d < 192; ++d) {
            float4 a = x4[d], b = y4[d];
            s += a.x * b.x + a.y * b.y + a.z * b.z + a.w * b.w;
        }
        v = s * 10.0f;                       // /temp
        if (task == 3 && j == i) v = -1e9f;  // self mask
        M[(size_t)i * nc + j] = v;
    }
    // row logsumexp over j < nc
    red[t] = (j < nc) ? v : -1e30f;
    __syncthreads();
    for (int off = 128; off > 0; off >>= 1) { if (t < off) red[t] = fmaxf(red[t], red[t + off]); __syncthreads(); }
    float mx = red[0];
    __syncthreads();
    red[t] = (j < nc) ? expf(v - mx) : 0.0f;
    __syncthreads();
    for (int off = 128; off > 0; off >>= 1) { if (t < off) red[t] += red[t + off]; __syncthreads(); }
    if (t == 0) lse_r[lseoff + i] = mx + logf(red[0]);
}

// ---------- column LSE for L1/L3/L4 ----------
__global__ __launch_bounds__(128) void k_collse(
    const float* __restrict__ L1, const float* __restrict__ L3, const float* __restrict__ L4,
    float* __restrict__ lse_c)
{
    __shared__ float sm[128];
    int blk = blockIdx.x; int mat = blk >> 7; int j = blk & 127; int i = threadIdx.x;
    const float* M = (mat == 0) ? L1 : (mat == 1 ? L3 : L4);
    float v = M[(size_t)i * 128 + j];
    sm[i] = v; __syncthreads();
    for (int off = 64; off > 0; off >>= 1) { if (i < off) sm[i] = fmaxf(sm[i], sm[i + off]); __syncthreads(); }
    float mx = sm[0]; __syncthreads();
    sm[i] = expf(v - mx); __syncthreads();
    for (int off = 64; off > 0; off >>= 1) { if (i < off) sm[i] += sm[i + off]; __syncthreads(); }
    if (i == 0) lse_c[mat * 128 + j] = mx + logf(sm[0]);
}

// ---------- big GEMM: S[8192, ldS] (bf16) = A[8192,768] @ B[ldS rows,768]^T ----------
__global__ __launch_bounds__(256) void k_gemm(
    const ushort_t* __restrict__ A, const ushort_t* __restrict__ B,
    ushort_t* __restrict__ S, int ldS, int K)
{
    __shared__ ushort_t As[128 * 64];
    __shared__ ushort_t Bs[128 * 64];
    const int t = threadIdx.x;
    const int lane = t & 63, w = t >> 6;
    const int wr = w >> 1, wc = w & 1;
    const int m0 = blockIdx.x * 128, n0 = blockIdx.y * 128;
    const int lr = lane & 15, lk = lane >> 4;

    f32x4 acc[4][4] = {};

    for (int k0 = 0; k0 < K; k0 += 64) {
        #pragma unroll
        for (int ii = 0; ii < 4; ++ii) {
            int idx = ii * 256 + t;
            int row = idx >> 3, kc = (idx & 7) * 8;
            __builtin_amdgcn_global_load_lds(
                (const GLB_AS void*)(A + (size_t)(m0 + row) * K + (k0 + kc)),
                (LDS_AS void*)(As + idx * 8), 16, 0, 0);
        }
        #pragma unroll
        for (int ii = 0; ii < 4; ++ii) {
            int idx = ii * 256 + t;
            int row = idx >> 3, kc = (idx & 7) * 8;
            __builtin_amdgcn_global_load_lds(
                (const GLB_AS void*)(B + (size_t)(n0 + row) * K + (k0 + kc)),
                (LDS_AS void*)(Bs + idx * 8), 16, 0, 0);
        }
        __syncthreads();
        #pragma unroll
        for (int kk = 0; kk < 2; ++kk) {
            short8 av[4], bv[4];
            #pragma unroll
            for (int f = 0; f < 4; ++f)
                av[f] = *(const short8*)(As + (wr * 64 + f * 16 + lr) * 64 + kk * 32 + lk * 8);
            #pragma unroll
            for (int f = 0; f < 4; ++f)
                bv[f] = *(const short8*)(Bs + (wc * 64 + f * 16 + lr) * 64 + kk * 32 + lk * 8);
            #pragma unroll
            for (int fr = 0; fr < 4; ++fr)
                #pragma unroll
                for (int fc = 0; fc < 4; ++fc)
                    acc[fr][fc] = __builtin_amdgcn_mfma_f32_16x16x32_bf16(av[fr], bv[fc], acc[fr][fc], 0, 0, 0);
        }
        __syncthreads();
    }
    #pragma unroll
    for (int fr = 0; fr < 4; ++fr) {
        #pragma unroll
        for (int fc = 0; fc < 4; ++fc) {
            int col = n0 + wc * 64 + fc * 16 + lr;
            #pragma unroll
            for (int q = 0; q < 4; ++q) {
                int row = m0 + wr * 64 + fr * 16 + lk * 4 + q;
                S[(size_t)row * ldS + col] = f2bf(acc[fr][fc][q]);
            }
        }
    }
}

// ---------- soft-DTW DP ----------
// lane = column j (32 cols), TWO problems per wave (half-wave each).
// Anti-diagonal step s: lane j computes R[i][j], i = s - j, i in [0,64).
//   left = R[i][j-1]  : lane j-1's rp   (previous step)  -> DPP wave_shr:1
//   up   = R[i-1][j]  : own rp
//   diag = R[i-1][j-1]: lane j-1's rp2  (two steps back)  -> DPP wave_shr:1
// j==0 lanes (0 and 32) get boundary fixup, which also masks the cross-problem
// leak at lane 32 under the whole-wave shift.
__global__ __launch_bounds__(256) void k_dtw(
    const ushort_t* __restrict__ S, float* __restrict__ Dm,
    int ldS, int g0, int GC)
{
    __shared__ ushort_t cst[4][2][2048];   // [wave][problem][64 rows * 32 cols] raw bf16 sim
    const float K10 = 14.4269504088896340f;   // 10 * log2(e): cost pre-scaled so softmin needs no muls
    const float BIG = 1e30f;
    const int t = threadIdx.x, lane = t & 63, w = t >> 6;
    const int j = lane & 31;     // column within my problem
    const int pr = lane >> 5;    // which of the wave's 2 problems this half-wave owns

    // stage both problems' 64x32 bf16 tiles into this wave's private LDS region
    #pragma unroll
    for (int prq = 0; prq < 2; ++prq) {
        int p = (blockIdx.x * 4 + w) * 2 + prq;
        int b = p / GC, gg = p - b * GC;
        const ushort_t* gbase = S + (size_t)(b * 64 + (lane >> 2)) * ldS + gg * 32 + (lane & 3) * 8;
        #pragma unroll
        for (int q = 0; q < 4; ++q) {
            __builtin_amdgcn_global_load_lds(
                (const GLB_AS void*)(gbase + (size_t)(q * 16) * ldS),
                (LDS_AS void*)((LDS_AS char*)&cst[w][prq][0] + q * 1024 + lane * 16),
                16, 0, 0);
        }
    }
    asm volatile("s_waitcnt vmcnt(0)" ::: "memory");  // per-wave private region: no barrier needed

    const ushort_t* myc = &cst[w][pr][0];
    float rp = BIG, rp2 = BIG;
    float dgj0 = 0.0f;                  // diag boundary for j==0: 0 at s==0, BIG after
    const bool isj0 = (j == 0);
    const int big_i = __float_as_int(BIG);

    #pragma unroll 5
    for (int s = 0; s < 95; ++s) {
        float up = __int_as_float(__builtin_amdgcn_update_dpp(
            big_i, __float_as_int(rp), 0x138, 0xF, 0xF, false));   // wave_shr:1
        float dg = __int_as_float(__builtin_amdgcn_update_dpp(
            big_i, __float_as_int(rp2), 0x138, 0xF, 0xF, false));
        if (isj0) { up = BIG; dg = dgj0; }
        int ii = s - j;
        int iic = ii < 0 ? 0 : (ii > 63 ? 63 : ii);                // v_med3: keep LDS addr in-bounds
        float sim = __uint_as_float(((uint32_t)myc[iic * 32 + j]) << 16);
        float c = fmaf(sim, -K10, K10);                            // K10 * (1 - sim)
        float mn, md, mx;
        asm("v_min3_f32 %0, %1, %2, %3" : "=v"(mn) : "v"(rp), "v"(up), "v"(dg));
        asm("v_med3_f32 %0, %1, %2, %3" : "=v"(md) : "v"(rp), "v"(up), "v"(dg));
        asm("v_max3_f32 %0, %1, %2, %3" : "=v"(mx) : "v"(rp), "v"(up), "v"(dg));
        // one exp2 term is always exp2(0)=1: sum = 1 + exp2(mn-md) + exp2(mn-mx)
        float e = __builtin_amdgcn_exp2f(mn - md) + __builtin_amdgcn_exp2f(mn - mx);
        float r = c + mn - __builtin_amdgcn_logf(1.0f + e);        // v_log_f32 is log2
        bool act = (unsigned)ii < 64u;
        rp2 = act ? rp : rp2;
        rp  = act ? r  : rp;
        dgj0 = BIG;
    }
    if (j == 31) {     // lanes 31 (pr=0) and 63 (pr=1) hold R[63][31]
        int p = (blockIdx.x * 4 + w) * 2 + pr;
        int b = p / GC, gg = p - b * GC;
        Dm[b * 128 + g0 + gg] = rp * (1.0f / K10);
    }
}

// ---------- finalize: all CE losses + DTW CE -> scalar ----------
__global__ __launch_bounds__(128) void k_finalize(
    const float* __restrict__ L1, const float* __restrict__ L3, const float* __restrict__ L4,
    const float* __restrict__ NT, const float* __restrict__ lse_r, const float* __restrict__ lse_c,
    const float* __restrict__ Dm, float* __restrict__ out)
{
    int i = threadIdx.x;
    float d1 = L1[(size_t)i * 128 + i];
    float l1 = 0.5f * ((lse_r[i] - d1) + (lse_c[i] - d1));
    float d3 = L3[(size_t)i * 128 + i];
    float l3 = 0.5f * ((lse_r[128 + i] - d3) + (lse_c[128 + i] - d3));
    float d4 = L4[(size_t)i * 128 + i];
    float l4 = 0.5f * ((lse_r[256 + i] - d4) + (lse_c[256 + i] - d4));
    float nt = 0.5f * (lse_r[384 + i] - NT[(size_t)i * 256 + i + 128])
             + 0.5f * (lse_r[384 + 128 + i] - NT[(size_t)(i + 128) * 256 + i]);
    float mxr = -1e30f, mxc = -1e30f;
    for (int j = 0; j < 128; ++j) {
        mxr = fmaxf(mxr, -10.0f * Dm[i * 128 + j]);
        mxc = fmaxf(mxc, -10.0f * Dm[j * 128 + i]);
    }
    float sr = 0.f, sc2 = 0.f;
    for (int j = 0; j < 128; ++j) {
        sr  += expf(-10.0f * Dm[i * 128 + j] - mxr);
        sc2 += expf(-10.0f * Dm[j * 128 + i] - mxc);
    }
    float dd = -10.0f * Dm[i * 128 + i];
    float ld = 0.5f * ((mxr + logf(sr) - dd) + (mxc + logf(sc2) - dd));
    float tot = l1 + l3 + l4 + nt + 0.1f * ld;
    #pragma unroll
    for (int o = 32; o > 0; o >>= 1) tot += __shfl_down(tot, o);
    __shared__ float sm[2];
    if ((i & 63) == 0) sm[i >> 6] = tot;
    __syncthreads();
    if (i == 0) out[0] = (sm[0] + sm[1]) / (128.0f * 5.0f);
}

extern "C" void kernel_launch(void* const* d_in, const int* in_sizes, int n_in,
                              void* d_out, int out_size, void* d_ws, size_t ws_size,
                              hipStream_t stream)
{
    (void)in_sizes; (void)n_in; (void)out_size;
    const float* video = (const float*)d_in[0];   // [128,768]
    const float* sent  = (const float*)d_in[1];   // [128,768]
    const float* cand  = (const float*)d_in[2];   // [128,32,768]
    const float* frame = (const float*)d_in[3];   // [128,64,768]
    // d_in[4] = pos_step: unused by the reference.

    char* ws = (char*)d_ws;
    size_t off = 0;
    auto alloc = [&](size_t b) { void* p = ws + off; off = (off + b + 255) & ~(size_t)255; return p; };
    float*    vn  = (float*)alloc((size_t)128 * 768 * 4);
    float*    tn  = (float*)alloc((size_t)128 * 768 * 4);
    float*    an  = (float*)alloc((size_t)128 * 768 * 4);
    ushort_t* Abf = (ushort_t*)alloc((size_t)8192 * 768 * 2);
    ushort_t* Bbf = (ushort_t*)alloc((size_t)4096 * 768 * 2);
    float*    L1  = (float*)alloc((size_t)128 * 128 * 4);
    float*    L3  = (float*)alloc((size_t)128 * 128 * 4);
    float*    L4  = (float*)alloc((size_t)128 * 128 * 4);
    float*    NT  = (float*)alloc((size_t)256 * 256 * 4);
    float*    lse_r = (float*)alloc((size_t)640 * 4);
    float*    lse_c = (float*)alloc((size_t)384 * 4);
    float*    Dm  = (float*)alloc((size_t)128 * 128 * 4);
    int Nch = 4096;                                  // S chunk width; shrink if ws too small
    while (Nch > 128 && off + (size_t)Nch * 8192 * 2 > ws_size) Nch >>= 1;
    ushort_t* S = (ushort_t*)alloc((size_t)Nch * 8192 * 2);

    k_norm_f32 <<<128, 256, 0, stream>>>(video, vn);
    k_norm_f32 <<<128, 256, 0, stream>>>(sent, tn);
    k_agg_norm <<<128, 256, 0, stream>>>(cand, an);
    k_norm_bf16<<<8192, 256, 0, stream>>>(frame, Abf);
    k_norm_bf16<<<4096, 256, 0, stream>>>(cand, Bbf);
    k_logits   <<<640, 256, 0, stream>>>(vn, tn, an, L1, L3, L4, NT, lse_r);
    k_collse   <<<384, 128, 0, stream>>>(L1, L3, L4, lse_c);
    for (int c0 = 0; c0 < 4096; c0 += Nch) {
        int GC = Nch / 32;
        k_gemm<<<dim3(64, Nch / 128), 256, 0, stream>>>(Abf, Bbf + (size_t)c0 * 768, S, Nch, 768);
        k_dtw <<<dim3(128 * GC / 8), 256, 0, stream>>>(S, Dm, Nch, c0 / 32, GC);
    }
    k_finalize <<<1, 128, 0, stream>>>(L1, L3, L4, NT, lse_r, lse_c, Dm, (float*)d_out);
}

// Round 3
// 198.526 us; speedup vs baseline: 1.3748x; 1.0553x over previous
//
#include <hip/hip_runtime.h>
#include <stdint.h>

typedef unsigned short ushort_t;
typedef __attribute__((ext_vector_type(4))) float f32x4;
typedef __attribute__((ext_vector_type(8))) short short8;

#define LDS_AS __attribute__((address_space(3)))
#define GLB_AS __attribute__((address_space(1)))

__device__ __forceinline__ ushort_t f2bf(float f) {
    uint32_t u = __float_as_uint(f);
    u += 0x7FFFu + ((u >> 16) & 1u);   // RNE
    return (ushort_t)(u >> 16);
}

__device__ __forceinline__ float blocksum256(float v) {
    __shared__ float sm[4];
    #pragma unroll
    for (int off = 32; off > 0; off >>= 1) v += __shfl_down(v, off);
    if ((threadIdx.x & 63) == 0) sm[threadIdx.x >> 6] = v;
    __syncthreads();
    float r = sm[0] + sm[1] + sm[2] + sm[3];
    __syncthreads();
    return r;
}

// ---------- l2-normalize rows of [nrows, 768] f32 -> f32 ----------
__global__ __launch_bounds__(256) void k_norm_f32(const float* __restrict__ src, float* __restrict__ dst) {
    int r = blockIdx.x, t = threadIdx.x;
    const float* x = src + (size_t)r * 768;
    float a0 = x[t], a1 = x[t + 256], a2 = x[t + 512];
    float ss = blocksum256(a0 * a0 + a1 * a1 + a2 * a2);
    float sc = 1.0f / fmaxf(sqrtf(ss), 1e-12f);
    float* d = dst + (size_t)r * 768;
    d[t] = a0 * sc; d[t + 256] = a1 * sc; d[t + 512] = a2 * sc;
}

// ---------- l2-normalize rows -> bf16 ----------
__global__ __launch_bounds__(256) void k_norm_bf16(const float* __restrict__ src, ushort_t* __restrict__ dst) {
    int r = blockIdx.x, t = threadIdx.x;
    const float* x = src + (size_t)r * 768;
    float a0 = x[t], a1 = x[t + 256], a2 = x[t + 512];
    float ss = blocksum256(a0 * a0 + a1 * a1 + a2 * a2);
    float sc = 1.0f / fmaxf(sqrtf(ss), 1e-12f);
    ushort_t* d = dst + (size_t)r * 768;
    d[t] = f2bf(a0 * sc); d[t + 256] = f2bf(a1 * sc); d[t + 512] = f2bf(a2 * sc);
}

// ---------- aggregate text: mean over 32 candidates, then l2norm ----------
__global__ __launch_bounds__(256) void k_agg_norm(const float* __restrict__ cand, float* __restrict__ an) {
    int b = blockIdx.x, t = threadIdx.x;
    const float* c = cand + (size_t)b * 32 * 768;
    float m0 = 0.f, m1 = 0.f, m2 = 0.f;
    for (int k = 0; k < 32; ++k) {
        const float* ck = c + k * 768;
        m0 += ck[t]; m1 += ck[t + 256]; m2 += ck[t + 512];
    }
    m0 *= (1.0f / 32.0f); m1 *= (1.0f / 32.0f); m2 *= (1.0f / 32.0f);
    float ss = blocksum256(m0 * m0 + m1 * m1 + m2 * m2);
    float sc = 1.0f / fmaxf(sqrtf(ss), 1e-12f);
    float* d = an + (size_t)b * 768;
    d[t] = m0 * sc; d[t + 256] = m1 * sc; d[t + 512] = m2 * sc;
}

// ---------- small logits matrices + row LSE ----------
__global__ __launch_bounds__(256) void k_logits(
    const float* __restrict__ vn, const float* __restrict__ tn, const float* __restrict__ an,
    float* __restrict__ L1, float* __restrict__ L3, float* __restrict__ L4, float* __restrict__ NT,
    float* __restrict__ lse_r)
{
    __shared__ __align__(16) float xrow[768];
    __shared__ float red[256];
    int blk = blockIdx.x, t = threadIdx.x;
    int task, i, nc; const float* xp; float* M; int lseoff;
    if (blk < 128)      { task = 0; i = blk;       nc = 128; xp = vn + (size_t)i * 768; M = L1; lseoff = 0; }
    else if (blk < 256) { task = 1; i = blk - 128; nc = 128; xp = vn + (size_t)i * 768; M = L3; lseoff = 128; }
    else if (blk < 384) { task = 2; i = blk - 256; nc = 128; xp = tn + (size_t)i * 768; M = L4; lseoff = 256; }
    else                { task = 3; i = blk - 384; nc = 256;
                          xp = (i < 128) ? vn + (size_t)i * 768 : tn + (size_t)(i - 128) * 768;
                          M = NT; lseoff = 384; }
    for (int d = t; d < 768; d += 256) xrow[d] = xp[d];
    __syncthreads();
    int j = t;
    float v = -1e30f;
    if (j < nc) {
        const float* yp;
        if (task == 0)      yp = tn + (size_t)j * 768;
        else if (task == 3) yp = (j < 128) ? vn + (size_t)j * 768 : tn + (size_t)(j - 128) * 768;
        else                yp = an + (size_t)j * 768;
        const float4* y4 = (const float4*)yp;
        const float4* x4 = (const float4*)xrow;
        float s = 0.0f;
        #pragma unroll 4
        for (int d = 0; d < 192; ++d) {
            float4 a = x4[d], b = y4[d];
            s += a.x * b.x + a.y * b.y + a.z * b.z + a.w * b.w;
        }
        v = s * 10.0f;                       // /temp
        if (task == 3 && j == i) v = -1e9f;  // self mask
        M[(size_t)i * nc + j] = v;
    }
    red[t] = (j < nc) ? v : -1e30f;
    __syncthreads();
    for (int off = 128; off > 0; off >>= 1) { if (t < off) red[t] = fmaxf(red[t], red[t + off]); __syncthreads(); }
    float mx = red[0];
    __syncthreads();
    red[t] = (j < nc) ? expf(v - mx) : 0.0f;
    __syncthreads();
    for (int off = 128; off > 0; off >>= 1) { if (t < off) red[t] += red[t + off]; __syncthreads(); }
    if (t == 0) lse_r[lseoff + i] = mx + logf(red[0]);
}

// ---------- column LSE for L1/L3/L4 ----------
__global__ __launch_bounds__(128) void k_collse(
    const float* __restrict__ L1, const float* __restrict__ L3, const float* __restrict__ L4,
    float* __restrict__ lse_c)
{
    __shared__ float sm[128];
    int blk = blockIdx.x; int mat = blk >> 7; int j = blk & 127; int i = threadIdx.x;
    const float* M = (mat == 0) ? L1 : (mat == 1 ? L3 : L4);
    float v = M[(size_t)i * 128 + j];
    sm[i] = v; __syncthreads();
    for (int off = 64; off > 0; off >>= 1) { if (i < off) sm[i] = fmaxf(sm[i], sm[i + off]); __syncthreads(); }
    float mx = sm[0]; __syncthreads();
    sm[i] = expf(v - mx); __syncthreads();
    for (int off = 64; off > 0; off >>= 1) { if (i < off) sm[i] += sm[i + off]; __syncthreads(); }
    if (i == 0) lse_c[mat * 128 + j] = mx + logf(sm[0]);
}

// ---------- FUSED: 128x128 GEMM tile (A[8192,768] @ B[4096,768]^T, bf16) + soft-DTW ----------
// A row = b*64 + f (video b, frame f); B row = b'*32 + c (text b', candidate c).
// A 128x128 tile therefore holds EXACTLY 8 complete DTW problems (2 b x 4 b'),
// and each wave's 64x64 quadrant holds exactly 2 -> wave-private DTW, no S matrix.
// DTW region row stride 66 (bf16): both the acc->LDS write pattern and the skewed
// DP read pattern land on <=2-way bank aliasing (free per m136).
__global__ __launch_bounds__(256) void k_gemm_dtw(
    const ushort_t* __restrict__ A, const ushort_t* __restrict__ B,
    float* __restrict__ Dm)
{
    __shared__ __align__(16) ushort_t lds[4 * 64 * 66];   // 33792 B >= 2*128*64 staging
    ushort_t* As = lds;
    ushort_t* Bs = lds + 128 * 64;
    const int t = threadIdx.x;
    const int lane = t & 63, w = t >> 6;
    const int wr = w >> 1, wc = w & 1;
    const int m0 = blockIdx.x * 128, n0 = blockIdx.y * 128;
    const int lr = lane & 15, lk = lane >> 4;
    const int K = 768;

    f32x4 acc[4][4] = {};

    for (int k0 = 0; k0 < K; k0 += 64) {
        #pragma unroll
        for (int ii = 0; ii < 4; ++ii) {
            int idx = ii * 256 + t;
            int row = idx >> 3, kc = (idx & 7) * 8;
            __builtin_amdgcn_global_load_lds(
                (const GLB_AS void*)(A + (size_t)(m0 + row) * K + (k0 + kc)),
                (LDS_AS void*)(As + idx * 8), 16, 0, 0);
        }
        #pragma unroll
        for (int ii = 0; ii < 4; ++ii) {
            int idx = ii * 256 + t;
            int row = idx >> 3, kc = (idx & 7) * 8;
            __builtin_amdgcn_global_load_lds(
                (const GLB_AS void*)(B + (size_t)(n0 + row) * K + (k0 + kc)),
                (LDS_AS void*)(Bs + idx * 8), 16, 0, 0);
        }
        __syncthreads();
        #pragma unroll
        for (int kk = 0; kk < 2; ++kk) {
            short8 av[4], bv[4];
            #pragma unroll
            for (int f = 0; f < 4; ++f)
                av[f] = *(const short8*)(As + (wr * 64 + f * 16 + lr) * 64 + kk * 32 + lk * 8);
            #pragma unroll
            for (int f = 0; f < 4; ++f)
                bv[f] = *(const short8*)(Bs + (wc * 64 + f * 16 + lr) * 64 + kk * 32 + lk * 8);
            #pragma unroll
            for (int fr = 0; fr < 4; ++fr)
                #pragma unroll
                for (int fc = 0; fc < 4; ++fc)
                    acc[fr][fc] = __builtin_amdgcn_mfma_f32_16x16x32_bf16(av[fr], bv[fc], acc[fr][fc], 0, 0, 0);
        }
        __syncthreads();
    }

    // ---- acc (sim, f32) -> wave-private LDS region as bf16; quadrant col == lane ----
    ushort_t* reg = lds + w * (64 * 66);
    #pragma unroll
    for (int fr = 0; fr < 4; ++fr)
        #pragma unroll
        for (int fc = 0; fc < 4; ++fc)
            #pragma unroll
            for (int q = 0; q < 4; ++q)
                reg[(fr * 16 + lk * 4 + q) * 66 + fc * 16 + lr] = f2bf(acc[fr][fc][q]);
    __syncthreads();   // LDS fence; waves run independently from here

    // ---- soft-DTW: lane = quadrant column (problem pr = lane>>5, col j = lane&31) ----
    const float K10 = 14.4269504088896340f;   // 10*log2(e): cost pre-scaled, softmin mul-free
    const float BIG = 1e30f;
    const int j = lane & 31;
    const int pr = lane >> 5;
    float rp = BIG, rp2 = BIG;
    float dgj0 = 0.0f;                  // diag boundary for j==0: 0 at s==0, BIG after
    const bool isj0 = (j == 0);
    const int big_i = __float_as_int(BIG);

    #pragma unroll 5
    for (int s = 0; s < 95; ++s) {
        float up = __int_as_float(__builtin_amdgcn_update_dpp(
            big_i, __float_as_int(rp), 0x138, 0xF, 0xF, false));   // wave_shr:1
        float dg = __int_as_float(__builtin_amdgcn_update_dpp(
            big_i, __float_as_int(rp2), 0x138, 0xF, 0xF, false));
        if (isj0) { up = BIG; dg = dgj0; }
        int ii = s - j;
        int iic = ii < 0 ? 0 : (ii > 63 ? 63 : ii);                // v_med3: keep LDS addr in-bounds
        float sim = __uint_as_float(((uint32_t)reg[iic * 66 + lane]) << 16);
        float c = fmaf(sim, -K10, K10);                            // K10 * (1 - sim)
        float mn, md, mx;
        asm("v_min3_f32 %0, %1, %2, %3" : "=v"(mn) : "v"(rp), "v"(up), "v"(dg));
        asm("v_med3_f32 %0, %1, %2, %3" : "=v"(md) : "v"(rp), "v"(up), "v"(dg));
        asm("v_max3_f32 %0, %1, %2, %3" : "=v"(mx) : "v"(rp), "v"(up), "v"(dg));
        float e = __builtin_amdgcn_exp2f(mn - md) + __builtin_amdgcn_exp2f(mn - mx);
        float r = c + mn - __builtin_amdgcn_logf(1.0f + e);        // v_log_f32 is log2
        bool act = (unsigned)ii < 64u;
        rp2 = act ? rp : rp2;
        rp  = act ? r  : rp;
        dgj0 = BIG;
    }
    if (j == 31) {     // lanes 31 (pr=0) and 63 (pr=1) hold R[63][31]
        int b  = blockIdx.x * 2 + wr;
        int bp = blockIdx.y * 4 + wc * 2 + pr;
        Dm[b * 128 + bp] = rp * (1.0f / K10);
    }
}

// ---------- finalize: all CE losses + DTW CE -> scalar ----------
__global__ __launch_bounds__(128) void k_finalize(
    const float* __restrict__ L1, const float* __restrict__ L3, const float* __restrict__ L4,
    const float* __restrict__ NT, const float* __restrict__ lse_r, const float* __restrict__ lse_c,
    const float* __restrict__ Dm, float* __restrict__ out)
{
    int i = threadIdx.x;
    float d1 = L1[(size_t)i * 128 + i];
    float l1 = 0.5f * ((lse_r[i] - d1) + (lse_c[i] - d1));
    float d3 = L3[(size_t)i * 128 + i];
    float l3 = 0.5f * ((lse_r[128 + i] - d3) + (lse_c[128 + i] - d3));
    float d4 = L4[(size_t)i * 128 + i];
    float l4 = 0.5f * ((lse_r[256 + i] - d4) + (lse_c[256 + i] - d4));
    float nt = 0.5f * (lse_r[384 + i] - NT[(size_t)i * 256 + i + 128])
             + 0.5f * (lse_r[384 + 128 + i] - NT[(size_t)(i + 128) * 256 + i]);
    float mxr = -1e30f, mxc = -1e30f;
    for (int j = 0; j < 128; ++j) {
        mxr = fmaxf(mxr, -10.0f * Dm[i * 128 + j]);
        mxc = fmaxf(mxc, -10.0f * Dm[j * 128 + i]);
    }
    float sr = 0.f, sc2 = 0.f;
    for (int j = 0; j < 128; ++j) {
        sr  += expf(-10.0f * Dm[i * 128 + j] - mxr);
        sc2 += expf(-10.0f * Dm[j * 128 + i] - mxc);
    }
    float dd = -10.0f * Dm[i * 128 + i];
    float ld = 0.5f * ((mxr + logf(sr) - dd) + (mxc + logf(sc2) - dd));
    float tot = l1 + l3 + l4 + nt + 0.1f * ld;
    #pragma unroll
    for (int o = 32; o > 0; o >>= 1) tot += __shfl_down(tot, o);
    __shared__ float sm[2];
    if ((i & 63) == 0) sm[i >> 6] = tot;
    __syncthreads();
    if (i == 0) out[0] = (sm[0] + sm[1]) / (128.0f * 5.0f);
}

extern "C" void kernel_launch(void* const* d_in, const int* in_sizes, int n_in,
                              void* d_out, int out_size, void* d_ws, size_t ws_size,
                              hipStream_t stream)
{
    (void)in_sizes; (void)n_in; (void)out_size; (void)ws_size;
    const float* video = (const float*)d_in[0];   // [128,768]
    const float* sent  = (const float*)d_in[1];   // [128,768]
    const float* cand  = (const float*)d_in[2];   // [128,32,768]
    const float* frame = (const float*)d_in[3];   // [128,64,768]
    // d_in[4] = pos_step: unused by the reference.

    char* ws = (char*)d_ws;
    size_t off = 0;
    auto alloc = [&](size_t b) { void* p = ws + off; off = (off + b + 255) & ~(size_t)255; return p; };
    float*    vn  = (float*)alloc((size_t)128 * 768 * 4);
    float*    tn  = (float*)alloc((size_t)128 * 768 * 4);
    float*    an  = (float*)alloc((size_t)128 * 768 * 4);
    ushort_t* Abf = (ushort_t*)alloc((size_t)8192 * 768 * 2);
    ushort_t* Bbf = (ushort_t*)alloc((size_t)4096 * 768 * 2);
    float*    L1  = (float*)alloc((size_t)128 * 128 * 4);
    float*    L3  = (float*)alloc((size_t)128 * 128 * 4);
    float*    L4  = (float*)alloc((size_t)128 * 128 * 4);
    float*    NT  = (float*)alloc((size_t)256 * 256 * 4);
    float*    lse_r = (float*)alloc((size_t)640 * 4);
    float*    lse_c = (float*)alloc((size_t)384 * 4);
    float*    Dm  = (float*)alloc((size_t)128 * 128 * 4);

    k_norm_f32 <<<128, 256, 0, stream>>>(video, vn);
    k_norm_f32 <<<128, 256, 0, stream>>>(sent, tn);
    k_agg_norm <<<128, 256, 0, stream>>>(cand, an);
    k_norm_bf16<<<8192, 256, 0, stream>>>(frame, Abf);
    k_norm_bf16<<<4096, 256, 0, stream>>>(cand, Bbf);
    k_logits   <<<640, 256, 0, stream>>>(vn, tn, an, L1, L3, L4, NT, lse_r);
    k_collse   <<<384, 128, 0, stream>>>(L1, L3, L4, lse_c);
    k_gemm_dtw <<<dim3(64, 32), 256, 0, stream>>>(Abf, Bbf, Dm);
    k_finalize <<<1, 128, 0, stream>>>(L1, L3, L4, NT, lse_r, lse_c, Dm, (float*)d_out);
}

// Round 4
// 172.714 us; speedup vs baseline: 1.5802x; 1.1494x over previous
//
#include <hip/hip_runtime.h>
#include <stdint.h>

typedef unsigned short ushort_t;
typedef __attribute__((ext_vector_type(4))) float f32x4;
typedef __attribute__((ext_vector_type(8))) short short8;

#define LDS_AS __attribute__((address_space(3)))
#define GLB_AS __attribute__((address_space(1)))

__device__ __forceinline__ ushort_t f2bf(float f) {
    uint32_t u = __float_as_uint(f);
    u += 0x7FFFu + ((u >> 16) & 1u);   // RNE
    return (ushort_t)(u >> 16);
}

__device__ __forceinline__ float bf2f(ushort_t u) {
    return __uint_as_float(((uint32_t)u) << 16);
}

__device__ __forceinline__ float dpp_shr1(float x) {   // lane l <- lane l-1 (wave_shr:1)
    return __int_as_float(__builtin_amdgcn_update_dpp(
        __float_as_int(1e30f), __float_as_int(x), 0x138, 0xF, 0xF, false));
}

__device__ __forceinline__ float blocksum256(float v) {
    __shared__ float sm[4];
    #pragma unroll
    for (int off = 32; off > 0; off >>= 1) v += __shfl_down(v, off);
    if ((threadIdx.x & 63) == 0) sm[threadIdx.x >> 6] = v;
    __syncthreads();
    float r = sm[0] + sm[1] + sm[2] + sm[3];
    __syncthreads();
    return r;
}

// ---------- prep: normalize video->vn, sent->tn, mean(cand)->an (f32) ----------
__global__ __launch_bounds__(256) void k_prep(
    const float* __restrict__ video, const float* __restrict__ sent,
    const float* __restrict__ cand,
    float* __restrict__ vn, float* __restrict__ tn, float* __restrict__ an)
{
    int r = blockIdx.x, t = threadIdx.x;
    float a0, a1, a2; float* d;
    if (r < 256) {
        const float* x = ((r < 128) ? video + (size_t)r * 768 : sent + (size_t)(r - 128) * 768);
        a0 = x[t]; a1 = x[t + 256]; a2 = x[t + 512];
        d = (r < 128) ? vn + (size_t)r * 768 : tn + (size_t)(r - 128) * 768;
    } else {
        int b = r - 256;
        const float* c = cand + (size_t)b * 32 * 768;
        a0 = a1 = a2 = 0.f;
        for (int k = 0; k < 32; ++k) {
            const float* ck = c + k * 768;
            a0 += ck[t]; a1 += ck[t + 256]; a2 += ck[t + 512];
        }
        a0 *= (1.0f / 32.0f); a1 *= (1.0f / 32.0f); a2 *= (1.0f / 32.0f);
        d = an + (size_t)b * 768;
    }
    float ss = blocksum256(a0 * a0 + a1 * a1 + a2 * a2);
    float sc = 1.0f / fmaxf(sqrtf(ss), 1e-12f);
    d[t] = a0 * sc; d[t + 256] = a1 * sc; d[t + 512] = a2 * sc;
}

// ---------- normalize rows -> bf16 (frame -> Abf, cand -> Bbf) ----------
__global__ __launch_bounds__(256) void k_tobf(
    const float* __restrict__ frame, const float* __restrict__ cand,
    ushort_t* __restrict__ Abf, ushort_t* __restrict__ Bbf)
{
    int r = blockIdx.x, t = threadIdx.x;
    const float* x; ushort_t* d;
    if (r < 8192) { x = frame + (size_t)r * 768; d = Abf + (size_t)r * 768; }
    else          { x = cand + (size_t)(r - 8192) * 768; d = Bbf + (size_t)(r - 8192) * 768; }
    float a0 = x[t], a1 = x[t + 256], a2 = x[t + 512];
    float ss = blocksum256(a0 * a0 + a1 * a1 + a2 * a2);
    float sc = 1.0f / fmaxf(sqrtf(ss), 1e-12f);
    d[t] = f2bf(a0 * sc); d[t + 256] = f2bf(a1 * sc); d[t + 512] = f2bf(a2 * sc);
}

// ---------- all CE logits: LSEs + diagonals, matrix-free ----------
// lse layout: [0..128) L1 row | [128..256) L1 col | [256..384) L3 row | [384..512) L3 col
//             [512..640) L4 row | [640..768) L4 col | [768..1024) NT rows (NT symmetric)
// diag: [0..128) d1=10*vn.tn | [128..256) d3=10*vn.an | [256..384) d4=10*tn.an
__global__ __launch_bounds__(256) void k_logits_all(
    const float* __restrict__ vn, const float* __restrict__ tn, const float* __restrict__ an,
    float* __restrict__ lse, float* __restrict__ diag)
{
    __shared__ __align__(16) float xs[8 * 768];
    __shared__ float vv[8 * 256];
    const int blk = blockIdx.x, t = threadIdx.x;
    int task, rb, nc;
    if (blk < 96) { task = blk >> 4; rb = blk & 15; nc = 128; }
    else          { task = 6; rb = blk - 96; nc = 256; }
    const int rowbase = rb * 8;

    // stage 8 x-rows
    for (int idx = t; idx < 8 * 768; idx += 256) {
        int r = idx / 768, k = idx - r * 768;
        int gi = rowbase + r;
        const float* xr;
        switch (task) {
            case 0: case 2: xr = vn + (size_t)gi * 768; break;
            case 1: case 4: xr = tn + (size_t)gi * 768; break;
            case 3: case 5: xr = an + (size_t)gi * 768; break;
            default: xr = (gi < 128) ? vn + (size_t)gi * 768 : tn + (size_t)(gi - 128) * 768;
        }
        xs[idx] = xr[k];
    }
    __syncthreads();

    if (t < nc) {
        const float* yr;
        switch (task) {
            case 0: yr = tn + (size_t)t * 768; break;
            case 1: yr = vn + (size_t)t * 768; break;
            case 2: yr = an + (size_t)t * 768; break;
            case 3: yr = vn + (size_t)t * 768; break;
            case 4: yr = an + (size_t)t * 768; break;
            case 5: yr = tn + (size_t)t * 768; break;
            default: yr = (t < 128) ? vn + (size_t)t * 768 : tn + (size_t)(t - 128) * 768;
        }
        const float4* y4 = (const float4*)yr;
        float a[8] = {};
        for (int k4 = 0; k4 < 192; ++k4) {
            float4 y = y4[k4];
            #pragma unroll
            for (int r = 0; r < 8; ++r) {
                const float4 x = *(const float4*)(xs + r * 768 + k4 * 4);
                a[r] += x.x * y.x + x.y * y.y + x.z * y.z + x.w * y.w;
            }
        }
        #pragma unroll
        for (int r = 0; r < 8; ++r) {
            float v = a[r] * 10.0f;
            if ((task == 0 || task == 2 || task == 4) && t == rowbase + r)
                diag[(task >> 1) * 128 + t] = v;
            if (task == 6 && t == rowbase + r) v = -1e30f;   // self mask
            vv[r * 256 + t] = v;
        }
    }
    __syncthreads();

    const int wv = t >> 6, ln = t & 63;
    #pragma unroll
    for (int h = 0; h < 2; ++h) {
        int r = wv * 2 + h;
        float m = -1e30f;
        for (int jj = ln; jj < nc; jj += 64) m = fmaxf(m, vv[r * 256 + jj]);
        #pragma unroll
        for (int off = 32; off > 0; off >>= 1) m = fmaxf(m, __shfl_xor(m, off));
        float s = 0.0f;
        for (int jj = ln; jj < nc; jj += 64) s += expf(vv[r * 256 + jj] - m);
        #pragma unroll
        for (int off = 32; off > 0; off >>= 1) s += __shfl_xor(s, off);
        if (ln == 0) {
            int o = (task < 6) ? task * 128 + rowbase + r : 768 + rowbase + r;
            lse[o] = m + logf(s);
        }
    }
}

// ---------- FUSED 256x256 GEMM (counted-vmcnt pipeline) + soft-DTW ----------
// A[8192,768] @ B[4096,768]^T, bf16 in, 8 waves (2M x 4N), per-wave 128x64 out.
// BK=32, 4 LDS K-tile buffers (stage t+3 while computing t): at iter t the 8
// newest outstanding loads are tiles t+1,t+2 -> s_waitcnt vmcnt(8) guarantees
// tile t resident. Barrier once per tile; vmcnt never drained in main loop.
// LDS chunk swizzle chunk^=(row>>1)&3, applied on the GLOBAL source (gload_lds
// writes linearly) and on the ds_read index -> fragment reads conflict-free.
// Epilogue: acc -> wave-private LDS (stride 66, <=2-way) -> two interleaved
// 95-step softmin DP chains (4 DTW problems per wave).
__global__ __launch_bounds__(512, 2) void k_gemm_dtw(
    const ushort_t* __restrict__ A, const ushort_t* __restrict__ B,
    float* __restrict__ Dm)
{
    __shared__ __align__(16) ushort_t lds[67584];   // 135168 B: 4x32KB staging, reused for DTW
    const int t = threadIdx.x;
    const int lane = t & 63, w = t >> 6;
    const int wr = w >> 2, wc = w & 3;              // 2M x 4N waves
    const int lr = lane & 15, lk = lane >> 4;
    const int axor = (lk ^ ((lr >> 1) & 3)) * 8;    // swizzled chunk offset (ushorts)
    const int m0 = blockIdx.x * 256, n0 = blockIdx.y * 256;

    f32x4 acc[8][4] = {};

#define STAGE(tile) { \
    const int sb_ = (tile) & 3; \
    ushort_t* ab_ = lds + sb_ * 16384; \
    ushort_t* bb_ = ab_ + 8192; \
    _Pragma("unroll") \
    for (int r_ = 0; r_ < 2; ++r_) { \
        int c_ = r_ * 512 + t; \
        int row_ = c_ >> 2, ch_ = c_ & 3; \
        int g_ = ch_ ^ ((row_ >> 1) & 3); \
        __builtin_amdgcn_global_load_lds( \
            (const GLB_AS void*)(A + (size_t)(m0 + row_) * 768 + (tile) * 32 + g_ * 8), \
            (LDS_AS void*)(ab_ + c_ * 8), 16, 0, 0); \
        __builtin_amdgcn_global_load_lds( \
            (const GLB_AS void*)(B + (size_t)(n0 + row_) * 768 + (tile) * 32 + g_ * 8), \
            (LDS_AS void*)(bb_ + c_ * 8), 16, 0, 0); \
    } }

#define KSTEP(tt, VMSTR, DO_STAGE) { \
    __builtin_amdgcn_sched_barrier(0); \
    asm volatile("s_waitcnt " VMSTR " lgkmcnt(0)" ::: "memory"); \
    __builtin_amdgcn_s_barrier(); \
    __builtin_amdgcn_sched_barrier(0); \
    if (DO_STAGE) STAGE((tt) + 3); \
    const ushort_t* ab = lds + ((tt) & 3) * 16384; \
    const ushort_t* bb = ab + 8192; \
    short8 av[8], bv[4]; \
    _Pragma("unroll") \
    for (int mf = 0; mf < 8; ++mf) \
        av[mf] = *(const short8*)(ab + (wr * 128 + mf * 16 + lr) * 32 + axor); \
    _Pragma("unroll") \
    for (int nf = 0; nf < 4; ++nf) \
        bv[nf] = *(const short8*)(bb + (wc * 64 + nf * 16 + lr) * 32 + axor); \
    __builtin_amdgcn_s_setprio(1); \
    _Pragma("unroll") \
    for (int mf = 0; mf < 8; ++mf) \
        _Pragma("unroll") \
        for (int nf = 0; nf < 4; ++nf) \
            acc[mf][nf] = __builtin_amdgcn_mfma_f32_16x16x32_bf16(av[mf], bv[nf], acc[mf][nf], 0, 0, 0); \
    __builtin_amdgcn_s_setprio(0); \
}

    STAGE(0); STAGE(1); STAGE(2);
    #pragma unroll 1
    for (int tt = 0; tt < 22; ++tt) {
        KSTEP(tt, "vmcnt(8)", tt < 21);
    }
    KSTEP(22, "vmcnt(4)", 0);
    KSTEP(23, "vmcnt(0)", 0);
#undef KSTEP
#undef STAGE

    __syncthreads();   // all staging reads done; safe to overwrite LDS with DTW scores

    // ---- acc (sim) -> wave-private LDS bf16, stride 66 ----
    ushort_t* dtw = lds + w * 8448;                 // 128 rows x 66
    #pragma unroll
    for (int mf = 0; mf < 8; ++mf)
        #pragma unroll
        for (int nf = 0; nf < 4; ++nf)
            #pragma unroll
            for (int q = 0; q < 4; ++q)
                dtw[(mf * 16 + lk * 4 + q) * 66 + nf * 16 + lr] = f2bf(acc[mf][nf][q]);

    // ---- soft-DTW: two interleaved chains (row-blocks 0..63 / 64..127) ----
    const float K10 = 14.4269504088896340f;   // 10*log2(e): mul-free softmin in scaled space
    const float BIG = 1e30f;
    const int j = lane & 31, pr = lane >> 5;
    const bool isj0 = (j == 0);
    float rpA = BIG, rp2A = BIG, rpB = BIG, rp2B = BIG;
    float dg0 = 0.0f;
    const ushort_t* dA = dtw;
    const ushort_t* dB = dtw + 64 * 66;

    #pragma unroll 5
    for (int s = 0; s < 95; ++s) {
        float upA = dpp_shr1(rpA), dgA = dpp_shr1(rp2A);
        float upB = dpp_shr1(rpB), dgB = dpp_shr1(rp2B);
        if (isj0) { upA = BIG; dgA = dg0; upB = BIG; dgB = dg0; }
        int ii = s - j;
        int iic = ii < 0 ? 0 : (ii > 63 ? 63 : ii);
        float cA = fmaf(bf2f(dA[iic * 66 + lane]), -K10, K10);   // K10*(1-sim)
        float cB = fmaf(bf2f(dB[iic * 66 + lane]), -K10, K10);
        float mnA, mdA, mxA, mnB, mdB, mxB;
        asm("v_min3_f32 %0, %1, %2, %3" : "=v"(mnA) : "v"(rpA), "v"(upA), "v"(dgA));
        asm("v_med3_f32 %0, %1, %2, %3" : "=v"(mdA) : "v"(rpA), "v"(upA), "v"(dgA));
        asm("v_max3_f32 %0, %1, %2, %3" : "=v"(mxA) : "v"(rpA), "v"(upA), "v"(dgA));
        asm("v_min3_f32 %0, %1, %2, %3" : "=v"(mnB) : "v"(rpB), "v"(upB), "v"(dgB));
        asm("v_med3_f32 %0, %1, %2, %3" : "=v"(mdB) : "v"(rpB), "v"(upB), "v"(dgB));
        asm("v_max3_f32 %0, %1, %2, %3" : "=v"(mxB) : "v"(rpB), "v"(upB), "v"(dgB));
        float eA = __builtin_amdgcn_exp2f(mnA - mdA) + __builtin_amdgcn_exp2f(mnA - mxA);
        float eB = __builtin_amdgcn_exp2f(mnB - mdB) + __builtin_amdgcn_exp2f(mnB - mxB);
        float rA = cA + mnA - __builtin_amdgcn_logf(1.0f + eA);
        float rB = cB + mnB - __builtin_amdgcn_logf(1.0f + eB);
        bool act = (unsigned)ii < 64u;
        rp2A = act ? rpA : rp2A; rpA = act ? rA : rpA;
        rp2B = act ? rpB : rp2B; rpB = act ? rB : rpB;
        dg0 = BIG;
    }
    if (j == 31) {     // lanes 31 (pr=0) and 63 (pr=1) hold R[63][31] of each chain
        int b0 = blockIdx.x * 4 + wr * 2;
        int bp = blockIdx.y * 8 + wc * 2 + pr;
        Dm[(size_t)b0 * 128 + bp]       = rpA * (1.0f / K10);
        Dm[(size_t)(b0 + 1) * 128 + bp] = rpB * (1.0f / K10);
    }
}

// ---------- finalize: all CE losses + DTW CE -> scalar ----------
__global__ __launch_bounds__(128) void k_finalize(
    const float* __restrict__ lse, const float* __restrict__ diag,
    const float* __restrict__ Dm, float* __restrict__ out)
{
    int i = threadIdx.x;
    float d1 = diag[i], d3 = diag[128 + i], d4 = diag[256 + i];
    float l1 = 0.5f * ((lse[i] - d1) + (lse[128 + i] - d1));
    float l3 = 0.5f * ((lse[256 + i] - d3) + (lse[384 + i] - d3));
    float l4 = 0.5f * ((lse[512 + i] - d4) + (lse[640 + i] - d4));
    float nt = 0.5f * (lse[768 + i] - d1) + 0.5f * (lse[896 + i] - d1);
    float mxr = -1e30f, mxc = -1e30f;
    for (int jj = 0; jj < 128; ++jj) {
        mxr = fmaxf(mxr, -10.0f * Dm[i * 128 + jj]);
        mxc = fmaxf(mxc, -10.0f * Dm[jj * 128 + i]);
    }
    float sr = 0.f, sc2 = 0.f;
    for (int jj = 0; jj < 128; ++jj) {
        sr  += expf(-10.0f * Dm[i * 128 + jj] - mxr);
        sc2 += expf(-10.0f * Dm[jj * 128 + i] - mxc);
    }
    float dd = -10.0f * Dm[i * 128 + i];
    float ld = 0.5f * ((mxr + logf(sr) - dd) + (mxc + logf(sc2) - dd));
    float tot = l1 + l3 + l4 + nt + 0.1f * ld;
    #pragma unroll
    for (int o = 32; o > 0; o >>= 1) tot += __shfl_down(tot, o);
    __shared__ float sm[2];
    if ((i & 63) == 0) sm[i >> 6] = tot;
    __syncthreads();
    if (i == 0) out[0] = (sm[0] + sm[1]) / (128.0f * 5.0f);
}

extern "C" void kernel_launch(void* const* d_in, const int* in_sizes, int n_in,
                              void* d_out, int out_size, void* d_ws, size_t ws_size,
                              hipStream_t stream)
{
    (void)in_sizes; (void)n_in; (void)out_size; (void)ws_size;
    const float* video = (const float*)d_in[0];   // [128,768]
    const float* sent  = (const float*)d_in[1];   // [128,768]
    const float* cand  = (const float*)d_in[2];   // [128,32,768]
    const float* frame = (const float*)d_in[3];   // [128,64,768]
    // d_in[4] = pos_step: unused by the reference.

    char* ws = (char*)d_ws;
    size_t off = 0;
    auto alloc = [&](size_t b) { void* p = ws + off; off = (off + b + 255) & ~(size_t)255; return p; };
    float*    vn   = (float*)alloc((size_t)128 * 768 * 4);
    float*    tn   = (float*)alloc((size_t)128 * 768 * 4);
    float*    an   = (float*)alloc((size_t)128 * 768 * 4);
    ushort_t* Abf  = (ushort_t*)alloc((size_t)8192 * 768 * 2);
    ushort_t* Bbf  = (ushort_t*)alloc((size_t)4096 * 768 * 2);
    float*    lse  = (float*)alloc((size_t)1024 * 4);
    float*    diag = (float*)alloc((size_t)384 * 4);
    float*    Dm   = (float*)alloc((size_t)128 * 128 * 4);

    k_tobf      <<<12288, 256, 0, stream>>>(frame, cand, Abf, Bbf);
    k_gemm_dtw  <<<dim3(32, 16), 512, 0, stream>>>(Abf, Bbf, Dm);
    k_prep      <<<384, 256, 0, stream>>>(video, sent, cand, vn, tn, an);
    k_logits_all<<<128, 256, 0, stream>>>(vn, tn, an, lse, diag);
    k_finalize  <<<1, 128, 0, stream>>>(lse, diag, Dm, (float*)d_out);
}

// Round 5
// 134.384 us; speedup vs baseline: 2.0310x; 1.2852x over previous
//
#include <hip/hip_runtime.h>
#include <stdint.h>

typedef unsigned short ushort_t;
typedef __attribute__((ext_vector_type(4))) float f32x4;
typedef __attribute__((ext_vector_type(8))) short short8;
typedef __attribute__((ext_vector_type(4))) ushort_t us4;

#define LDS_AS __attribute__((address_space(3)))
#define GLB_AS __attribute__((address_space(1)))

__device__ __forceinline__ ushort_t f2bf(float f) {
    uint32_t u = __float_as_uint(f);
    u += 0x7FFFu + ((u >> 16) & 1u);   // RNE
    return (ushort_t)(u >> 16);
}

__device__ __forceinline__ float bf2f(ushort_t u) {
    return __uint_as_float(((uint32_t)u) << 16);
}

__device__ __forceinline__ float dpp_shr1(float x) {   // lane l <- lane l-1 (wave_shr:1)
    return __int_as_float(__builtin_amdgcn_update_dpp(
        __float_as_int(1e30f), __float_as_int(x), 0x138, 0xF, 0xF, false));
}

__device__ __forceinline__ float blocksum256(float v) {
    __shared__ float sm[4];
    #pragma unroll
    for (int off = 32; off > 0; off >>= 1) v += __shfl_down(v, off);
    if ((threadIdx.x & 63) == 0) sm[threadIdx.x >> 6] = v;
    __syncthreads();
    float r = sm[0] + sm[1] + sm[2] + sm[3];
    __syncthreads();
    return r;
}

// ---------- prep: all row-normalizations -> bf16, fully float4-vectorized ----------
// blocks [0,8192): frame->Abf | [8192,12288): cand->Bbf | [12288,12416): video->Z[0:128)
// [12416,12544): sent->Z[128:256) | [12544,12672): mean(cand_b)->Z[256:384)
__global__ __launch_bounds__(256) void k_prep_all(
    const float* __restrict__ frame, const float* __restrict__ cand,
    const float* __restrict__ video, const float* __restrict__ sent,
    ushort_t* __restrict__ Abf, ushort_t* __restrict__ Bbf, ushort_t* __restrict__ Zbf)
{
    const int r = blockIdx.x, t = threadIdx.x;
    float4 x = make_float4(0.f, 0.f, 0.f, 0.f);
    ushort_t* dst;
    if (r < 8192) {
        if (t < 192) x = ((const float4*)(frame + (size_t)r * 768))[t];
        dst = Abf + (size_t)r * 768;
    } else if (r < 12288) {
        int q = r - 8192;
        if (t < 192) x = ((const float4*)(cand + (size_t)q * 768))[t];
        dst = Bbf + (size_t)q * 768;
    } else if (r < 12416) {
        int q = r - 12288;
        if (t < 192) x = ((const float4*)(video + (size_t)q * 768))[t];
        dst = Zbf + (size_t)q * 768;
    } else if (r < 12544) {
        int q = r - 12416;
        if (t < 192) x = ((const float4*)(sent + (size_t)q * 768))[t];
        dst = Zbf + (size_t)(128 + q) * 768;
    } else {
        int b = r - 12544;
        if (t < 192) {
            for (int k = 0; k < 32; ++k) {
                float4 y = ((const float4*)(cand + (size_t)(b * 32 + k) * 768))[t];
                x.x += y.x; x.y += y.y; x.z += y.z; x.w += y.w;
            }
            x.x *= (1.f/32.f); x.y *= (1.f/32.f); x.z *= (1.f/32.f); x.w *= (1.f/32.f);
        }
        dst = Zbf + (size_t)(256 + b) * 768;
    }
    float ss = blocksum256(x.x*x.x + x.y*x.y + x.z*x.z + x.w*x.w);
    float sc = 1.0f / fmaxf(sqrtf(ss), 1e-12f);
    if (t < 192) {
        us4 u;
        u.x = f2bf(x.x * sc); u.y = f2bf(x.y * sc);
        u.z = f2bf(x.z * sc); u.w = f2bf(x.w * sc);
        *(us4*)(dst + t * 4) = u;
    }
}

// ---------- Gram: G = 10 * Z @ Z^T, Z=[vn;tn;an] 384x768 bf16, G f32 384x384 ----------
// 128x128 tiles, 3x3 grid; R3-proven single-buffer structure.
__global__ __launch_bounds__(256) void k_gram(const ushort_t* __restrict__ Z, float* __restrict__ G)
{
    __shared__ __align__(16) ushort_t As[128 * 64];
    __shared__ __align__(16) ushort_t Bs[128 * 64];
    const int t = threadIdx.x;
    const int lane = t & 63, w = t >> 6;
    const int wr = w >> 1, wc = w & 1;
    const int m0 = blockIdx.x * 128, n0 = blockIdx.y * 128;
    const int lr = lane & 15, lk = lane >> 4;

    f32x4 acc[4][4] = {};

    for (int k0 = 0; k0 < 768; k0 += 64) {
        #pragma unroll
        for (int ii = 0; ii < 4; ++ii) {
            int idx = ii * 256 + t;
            int row = idx >> 3, kc = (idx & 7) * 8;
            __builtin_amdgcn_global_load_lds(
                (const GLB_AS void*)(Z + (size_t)(m0 + row) * 768 + (k0 + kc)),
                (LDS_AS void*)(As + idx * 8), 16, 0, 0);
        }
        #pragma unroll
        for (int ii = 0; ii < 4; ++ii) {
            int idx = ii * 256 + t;
            int row = idx >> 3, kc = (idx & 7) * 8;
            __builtin_amdgcn_global_load_lds(
                (const GLB_AS void*)(Z + (size_t)(n0 + row) * 768 + (k0 + kc)),
                (LDS_AS void*)(Bs + idx * 8), 16, 0, 0);
        }
        __syncthreads();
        #pragma unroll
        for (int kk = 0; kk < 2; ++kk) {
            short8 av[4], bv[4];
            #pragma unroll
            for (int f = 0; f < 4; ++f)
                av[f] = *(const short8*)(As + (wr * 64 + f * 16 + lr) * 64 + kk * 32 + lk * 8);
            #pragma unroll
            for (int f = 0; f < 4; ++f)
                bv[f] = *(const short8*)(Bs + (wc * 64 + f * 16 + lr) * 64 + kk * 32 + lk * 8);
            #pragma unroll
            for (int fr = 0; fr < 4; ++fr)
                #pragma unroll
                for (int fc = 0; fc < 4; ++fc)
                    acc[fr][fc] = __builtin_amdgcn_mfma_f32_16x16x32_bf16(av[fr], bv[fc], acc[fr][fc], 0, 0, 0);
        }
        __syncthreads();
    }
    #pragma unroll
    for (int fr = 0; fr < 4; ++fr)
        #pragma unroll
        for (int fc = 0; fc < 4; ++fc) {
            int col = n0 + wc * 64 + fc * 16 + lr;
            #pragma unroll
            for (int q = 0; q < 4; ++q) {
                int row = m0 + wr * 64 + fr * 16 + lk * 4 + q;
                G[(size_t)row * 384 + col] = 10.0f * acc[fr][fc][q];
            }
        }
}

// ---------- all LSEs from G (symmetry: col-LSE of block (a,b) = row-LSE of block (b,a)) ----
// lse: [0,128) L1row | [128,256) L1col | [256,384) L3row | [384,512) L3col
//      [512,640) L4row | [640,768) L4col | [768,1024) NT rows
__global__ __launch_bounds__(256) void k_lse(const float* __restrict__ G, float* __restrict__ lse)
{
    const int w = threadIdx.x >> 6, ln = threadIdx.x & 63;
    const int tid = blockIdx.x * 4 + w;
    int row, c0, nc, maskc = -1;
    if      (tid < 128) { row = tid;       c0 = 128; nc = 128; }
    else if (tid < 256) { row = tid;       c0 = 0;   nc = 128; }
    else if (tid < 384) { row = tid - 256; c0 = 256; nc = 128; }
    else if (tid < 512) { row = tid - 128; c0 = 0;   nc = 128; }
    else if (tid < 640) { row = tid - 384; c0 = 256; nc = 128; }
    else if (tid < 768) { row = tid - 384; c0 = 128; nc = 128; }
    else                { row = tid - 768; c0 = 0;   nc = 256; maskc = tid - 768; }
    const float* g = G + (size_t)row * 384 + c0;
    const int cnt = nc >> 6;
    float vals[4];
    #pragma unroll
    for (int q = 0; q < 4; ++q) {
        int c = q * 64 + ln;
        vals[q] = (q < cnt) ? g[c] : -1e30f;
        if (c == maskc) vals[q] = -1e30f;       // NT self-mask (c0==0 there)
    }
    float m = fmaxf(fmaxf(vals[0], vals[1]), fmaxf(vals[2], vals[3]));
    #pragma unroll
    for (int off = 32; off > 0; off >>= 1) m = fmaxf(m, __shfl_xor(m, off));
    float s = 0.f;
    #pragma unroll
    for (int q = 0; q < 4; ++q) s += expf(vals[q] - m);
    #pragma unroll
    for (int off = 32; off > 0; off >>= 1) s += __shfl_xor(s, off);
    if (ln == 0) lse[tid] = m + logf(s);
}

// ---------- FUSED 256x256 GEMM + soft-DTW, 16 waves of 64x64, 4 waves/SIMD ----------
// BK=32, 2 LDS buffers, counted vmcnt(2) (never drained in main loop), 2 barriers/step.
// Per-wave regs ~ 64 AGPR acc + ~50 VGPR <= 128 -> 4 waves/SIMD (__launch_bounds__(1024,4)).
// DTW: per-wave transposed LDS tile [64 cols][68] (b64-aligned writes; 2-way-free reads),
// one 95-step chain, 2 problems per wave (half-wave pr).
__global__ __launch_bounds__(1024, 4) void k_gemm_dtw(
    const ushort_t* __restrict__ A, const ushort_t* __restrict__ B,
    float* __restrict__ Dm)
{
    __shared__ __align__(16) ushort_t lds[69632];   // 139264 B; staging overlay = 2 x 32 KB at front
    const int t = threadIdx.x;
    const int lane = t & 63, w = t >> 6;            // 16 waves
    const int wr = w >> 2, wc = w & 3;              // 4x4 wave grid, each 64x64
    const int lr = lane & 15, lk = lane >> 4;
    const int axor = (lk ^ ((lr >> 1) & 3)) * 8;    // chunk-XOR (matches staging swizzle)
    // XCD swizzle: each XCD owns a 4-tile M strip (A-panel 1.5 MB -> resident in its L2)
    const int lin = blockIdx.y * 32 + blockIdx.x;
    const int xcd = lin & 7, idx = lin >> 3;
    const int m0 = (xcd * 4 + (idx & 3)) * 256;
    const int n0 = (idx >> 2) * 256;

    f32x4 acc[4][4] = {};

    const int srow = t >> 2, sch = t & 3;
    const int sg = (sch ^ ((srow >> 1) & 3)) * 8;   // pre-swizzled global source chunk
    const ushort_t* gA = A + (size_t)(m0 + srow) * 768 + sg;
    const ushort_t* gB = B + (size_t)(n0 + srow) * 768 + sg;

#define STAGE(tile) { \
    ushort_t* base_ = lds + ((tile) & 1) * 16384; \
    __builtin_amdgcn_global_load_lds((const GLB_AS void*)(gA + (tile) * 32), \
        (LDS_AS void*)(base_ + t * 8), 16, 0, 0); \
    __builtin_amdgcn_global_load_lds((const GLB_AS void*)(gB + (tile) * 32), \
        (LDS_AS void*)(base_ + 8192 + t * 8), 16, 0, 0); \
}

#define KSTEP(tt, VMSTR, DO_STAGE) { \
    asm volatile("s_waitcnt " VMSTR ::: "memory"); \
    __builtin_amdgcn_s_barrier(); \
    const ushort_t* ab = lds + ((tt) & 1) * 16384; \
    const ushort_t* bb = ab + 8192; \
    short8 av[4], bv[4]; \
    _Pragma("unroll") \
    for (int f = 0; f < 4; ++f) av[f] = *(const short8*)(ab + (wr * 64 + f * 16 + lr) * 32 + axor); \
    _Pragma("unroll") \
    for (int f = 0; f < 4; ++f) bv[f] = *(const short8*)(bb + (wc * 64 + f * 16 + lr) * 32 + axor); \
    asm volatile("s_waitcnt lgkmcnt(0)" ::: "memory"); \
    __builtin_amdgcn_sched_barrier(0); \
    __builtin_amdgcn_s_barrier(); \
    if (DO_STAGE) STAGE((tt) + 2); \
    __builtin_amdgcn_s_setprio(1); \
    _Pragma("unroll") \
    for (int mf = 0; mf < 4; ++mf) \
        _Pragma("unroll") \
        for (int nf = 0; nf < 4; ++nf) \
            acc[mf][nf] = __builtin_amdgcn_mfma_f32_16x16x32_bf16(av[mf], bv[nf], acc[mf][nf], 0, 0, 0); \
    __builtin_amdgcn_s_setprio(0); \
}

    STAGE(0); STAGE(1);
    #pragma unroll 1
    for (int tt = 0; tt < 22; ++tt) KSTEP(tt, "vmcnt(2)", 1)
    KSTEP(22, "vmcnt(2)", 0)
    KSTEP(23, "vmcnt(0)", 0)
#undef KSTEP
#undef STAGE

    __syncthreads();   // all waves done reading staging LDS; safe to overlay DTW tiles

    // ---- acc (sim) -> wave-private transposed LDS tile [col][row], stride 68, b64 writes ----
    ushort_t* dtwT = lds + w * 4352;                // 64 x 68 ushorts per wave
    #pragma unroll
    for (int nf = 0; nf < 4; ++nf)
        #pragma unroll
        for (int mf = 0; mf < 4; ++mf) {
            us4 pk;
            pk.x = f2bf(acc[mf][nf][0]); pk.y = f2bf(acc[mf][nf][1]);
            pk.z = f2bf(acc[mf][nf][2]); pk.w = f2bf(acc[mf][nf][3]);
            *(us4*)(dtwT + (nf * 16 + lr) * 68 + mf * 16 + lk * 4) = pk;
        }

    // ---- soft-DTW: one 95-step chain; lane = col (pr = problem, j = col in problem) ----
    const float K10 = 14.4269504088896340f;   // 10*log2(e): cost pre-scaled, mul-free softmin
    const float BIG = 1e30f;
    const int j = lane & 31, pr = lane >> 5;
    const bool isj0 = (j == 0);
    const ushort_t* base = dtwT + lane * 68;  // this lane's column, rows contiguous
    float rp = BIG, rp2 = BIG, dg0 = 0.0f;

    #pragma unroll 5
    for (int s = 0; s < 95; ++s) {
        float up = dpp_shr1(rp);
        float dg = dpp_shr1(rp2);
        if (isj0) { up = BIG; dg = dg0; }
        int ii = s - j;
        int iic = ii < 0 ? 0 : (ii > 63 ? 63 : ii);
        float c = fmaf(bf2f(base[iic]), -K10, K10);              // K10*(1-sim)
        float mn, md, mx;
        asm("v_min3_f32 %0, %1, %2, %3" : "=v"(mn) : "v"(rp), "v"(up), "v"(dg));
        asm("v_med3_f32 %0, %1, %2, %3" : "=v"(md) : "v"(rp), "v"(up), "v"(dg));
        asm("v_max3_f32 %0, %1, %2, %3" : "=v"(mx) : "v"(rp), "v"(up), "v"(dg));
        float e = __builtin_amdgcn_exp2f(mn - md) + __builtin_amdgcn_exp2f(mn - mx);
        float r = c + mn - __builtin_amdgcn_logf(1.0f + e);      // v_log_f32 = log2
        bool act = (unsigned)ii < 64u;
        rp2 = act ? rp : rp2;
        rp  = act ? r  : rp;
        dg0 = BIG;
    }
    if (j == 31) {   // lanes 31 (pr=0) and 63 (pr=1) hold R[63][31]
        int b  = (m0 >> 6) + wr;                  // video batch
        int bp = (n0 >> 5) + wc * 2 + pr;         // text batch
        Dm[(size_t)b * 128 + bp] = rp * (1.0f / K10);
    }
}

// ---------- finalize: CE losses (from G diag + lse) + DTW CE -> scalar ----------
__global__ __launch_bounds__(128) void k_finalize(
    const float* __restrict__ G, const float* __restrict__ lse,
    const float* __restrict__ Dm, float* __restrict__ out)
{
    int i = threadIdx.x;
    float d1 = G[(size_t)i * 384 + 128 + i];
    float d3 = G[(size_t)i * 384 + 256 + i];
    float d4 = G[(size_t)(128 + i) * 384 + 256 + i];
    float l1 = 0.5f * ((lse[i] - d1) + (lse[128 + i] - d1));
    float l3 = 0.5f * ((lse[256 + i] - d3) + (lse[384 + i] - d3));
    float l4 = 0.5f * ((lse[512 + i] - d4) + (lse[640 + i] - d4));
    float nt = 0.5f * (lse[768 + i] - d1) + 0.5f * (lse[896 + i] - d1);
    float mxr = -1e30f, mxc = -1e30f;
    for (int jj = 0; jj < 128; ++jj) {
        mxr = fmaxf(mxr, -10.0f * Dm[i * 128 + jj]);
        mxc = fmaxf(mxc, -10.0f * Dm[jj * 128 + i]);
    }
    float sr = 0.f, sc2 = 0.f;
    for (int jj = 0; jj < 128; ++jj) {
        sr  += expf(-10.0f * Dm[i * 128 + jj] - mxr);
        sc2 += expf(-10.0f * Dm[jj * 128 + i] - mxc);
    }
    float dd = -10.0f * Dm[i * 128 + i];
    float ld = 0.5f * ((mxr + logf(sr) - dd) + (mxc + logf(sc2) - dd));
    float tot = l1 + l3 + l4 + nt + 0.1f * ld;
    #pragma unroll
    for (int o = 32; o > 0; o >>= 1) tot += __shfl_down(tot, o);
    __shared__ float sm[2];
    if ((i & 63) == 0) sm[i >> 6] = tot;
    __syncthreads();
    if (i == 0) out[0] = (sm[0] + sm[1]) / (128.0f * 5.0f);
}

extern "C" void kernel_launch(void* const* d_in, const int* in_sizes, int n_in,
                              void* d_out, int out_size, void* d_ws, size_t ws_size,
                              hipStream_t stream)
{
    (void)in_sizes; (void)n_in; (void)out_size; (void)ws_size;
    const float* video = (const float*)d_in[0];   // [128,768]
    const float* sent  = (const float*)d_in[1];   // [128,768]
    const float* cand  = (const float*)d_in[2];   // [128,32,768]
    const float* frame = (const float*)d_in[3];   // [128,64,768]
    // d_in[4] = pos_step: unused by the reference.

    char* ws = (char*)d_ws;
    size_t off = 0;
    auto alloc = [&](size_t b) { void* p = ws + off; off = (off + b + 255) & ~(size_t)255; return p; };
    ushort_t* Abf = (ushort_t*)alloc((size_t)8192 * 768 * 2);
    ushort_t* Bbf = (ushort_t*)alloc((size_t)4096 * 768 * 2);
    ushort_t* Zbf = (ushort_t*)alloc((size_t)384 * 768 * 2);
    float*    G   = (float*)alloc((size_t)384 * 384 * 4);
    float*    lse = (float*)alloc((size_t)1024 * 4);
    float*    Dm  = (float*)alloc((size_t)128 * 128 * 4);

    k_prep_all <<<12672, 256, 0, stream>>>(frame, cand, video, sent, Abf, Bbf, Zbf);
    k_gemm_dtw <<<dim3(32, 16), 1024, 0, stream>>>(Abf, Bbf, Dm);
    k_gram     <<<dim3(3, 3), 256, 0, stream>>>(Zbf, G);
    k_lse      <<<256, 256, 0, stream>>>(G, lse);
    k_finalize <<<1, 128, 0, stream>>>(G, lse, Dm, (float*)d_out);
}